// Round 3
// baseline (1235.703 us; speedup 1.0000x reference)
//
#include <hip/hip_runtime.h>

// x:   (2,4,8,8,8,96,96) fp32   strides: b 18874368, ci 4718592, cd 589824, t 73728, d 9216, h 96, w 1
// W:   (9,4,4,3,3,3)     fp32   strides: ij 432, o 108, ci 27, kd 9, kh 3, kw 1
// b:   (9,4)             fp32
// out: (2,4,6,6,8,96,96) fp32   strides: b 10616832, o 2654208, c 442368, t 73728, d 9216, h 96, w 1

#define BLOCK 256

// Zero-initialized device buffer: invalid (out-of-range kd/kh) rows pointer-select
// here instead of per-element cndmask zeroing. .bss => zeroed at module load,
// never written.
__device__ __attribute__((aligned(16))) float g_zero[64];

struct Row { float e0; float4 a; float4 b; float e9; };

__device__ __forceinline__ Row load_row(const float* p, int eo0, int eo9,
                                         bool we0, bool we9) {
    Row r;
    r.e0 = p[eo0];
    r.a  = *(const float4*)p;
    r.b  = *(const float4*)(p + 4);
    r.e9 = p[eo9];
    r.e0 = we0 ? r.e0 : 0.f;
    r.e9 = we9 ? r.e9 : 0.f;
    return r;
}

// acc: a{o}l = w0..3, a{o}h = w4..7 for output channel o
#define FMA8(X0,X1,X2,X3,X4,X5,X6,X7,W) \
  a0l.x=fmaf(X0,W.x,a0l.x); a1l.x=fmaf(X0,W.y,a1l.x); a2l.x=fmaf(X0,W.z,a2l.x); a3l.x=fmaf(X0,W.w,a3l.x); \
  a0l.y=fmaf(X1,W.x,a0l.y); a1l.y=fmaf(X1,W.y,a1l.y); a2l.y=fmaf(X1,W.z,a2l.y); a3l.y=fmaf(X1,W.w,a3l.y); \
  a0l.z=fmaf(X2,W.x,a0l.z); a1l.z=fmaf(X2,W.y,a1l.z); a2l.z=fmaf(X2,W.z,a2l.z); a3l.z=fmaf(X2,W.w,a3l.z); \
  a0l.w=fmaf(X3,W.x,a0l.w); a1l.w=fmaf(X3,W.y,a1l.w); a2l.w=fmaf(X3,W.z,a2l.w); a3l.w=fmaf(X3,W.w,a3l.w); \
  a0h.x=fmaf(X4,W.x,a0h.x); a1h.x=fmaf(X4,W.y,a1h.x); a2h.x=fmaf(X4,W.z,a2h.x); a3h.x=fmaf(X4,W.w,a3h.x); \
  a0h.y=fmaf(X5,W.x,a0h.y); a1h.y=fmaf(X5,W.y,a1h.y); a2h.y=fmaf(X5,W.z,a2h.y); a3h.y=fmaf(X5,W.w,a3h.y); \
  a0h.z=fmaf(X6,W.x,a0h.z); a1h.z=fmaf(X6,W.y,a1h.z); a2h.z=fmaf(X6,W.z,a2h.z); a3h.z=fmaf(X6,W.w,a3h.z); \
  a0h.w=fmaf(X7,W.x,a0h.w); a1h.w=fmaf(X7,W.y,a1h.w); a2h.w=fmaf(X7,W.z,a2h.w); a3h.w=fmaf(X7,W.w,a3h.w);

#define ROWC(R, WQ) do { \
    float4 w0_ = ((const float4*)(WQ))[0]; \
    float4 w1_ = ((const float4*)(WQ))[1]; \
    float4 w2_ = ((const float4*)(WQ))[2]; \
    FMA8(R.e0,  R.a.x, R.a.y, R.a.z, R.a.w, R.b.x, R.b.y, R.b.z, w0_); \
    FMA8(R.a.x, R.a.y, R.a.z, R.a.w, R.b.x, R.b.y, R.b.z, R.b.w, w1_); \
    FMA8(R.a.y, R.a.z, R.a.w, R.b.x, R.b.y, R.b.z, R.b.w, R.e9,  w2_); \
  } while (0)

// launch_bounds(256,2): cap at 2 waves/EU minimum => up to 256 VGPRs, room for
// the 6-row pipeline (60 floats) + 32 accumulators without spilling.
__global__ __launch_bounds__(256, 2) void conv5d_kernel(
    const float* __restrict__ xg,
    const float* __restrict__ Wg,
    const float* __restrict__ bg,
    float* __restrict__ outg)
{
    // Weights in LDS, transposed: wl[ci][ij][q=kd*3+kh][kw][o] (o contiguous
    // => broadcast ds_read_b128 per (q,kw); 0 bank conflicts measured)
    __shared__ float wl[3888];
    for (int k = threadIdx.x; k < 3888; k += BLOCK) {
        int o  = k & 3;  int r = k >> 2;
        int kw = r % 3;  r /= 3;
        int kh = r % 3;  r /= 3;
        int kd = r % 3;  r /= 3;
        int ij = r % 9;  int ci = r / 9;
        wl[k] = Wg[ij*432 + o*108 + ci*27 + kd*9 + kh*3 + kw];
    }
    __syncthreads();

    // XCD-aware mapping: blockIdx round-robins across 8 XCDs (heuristic), so
    // give each XCD a contiguous group of 9 (b,c,t) slabs -> its co-resident
    // blocks read ~9 x-planes (~2.7 MB) per loop step, fitting the 4 MB L2.
    int bi    = blockIdx.x;          // 0..2591
    int xcd   = bi & 7;
    int local = bi >> 3;             // 0..323
    int slab  = xcd * 9 + (local / 36);   // 0..71 = (b,c,t)
    int pos   = local % 36;               // block within slab
    int b  = slab / 36;
    int ct = slab % 36;
    int c  = ct / 6;
    int t  = ct % 6;
    int tid = pos * BLOCK + (int)threadIdx.x;   // 0..9215
    int wv  = tid % 12;
    int h   = (tid / 12) % 96;
    int d   = tid / 1152;            // 0..7 (wave-uniform: 1152 = 18*64)
    int w0  = wv * 8;

    const float* xb = xg + (size_t)b * 18874368 + w0;
    const float* zb = &g_zero[4];    // +-1..+9 float offsets stay in zeros

    // Row validity masks and plane/row offsets (unclamped; invalid rows select zb)
    bool v00,v01,v02,v10,v11,v12,v20,v21,v22;
    int  o00,o01,o02,o10,o11,o12,o20,o21,o22;
    {
        bool vd0 = (d > 0), vd2 = (d < 7);
        bool vh0 = (h > 0), vh2 = (h < 95);
        int dd0 = (d-1)*9216, dd1 = d*9216, dd2 = (d+1)*9216;
        int hh0 = (h-1)*96,   hh1 = h*96,   hh2 = (h+1)*96;
        v00 = vd0 && vh0; o00 = dd0 + hh0;
        v01 = vd0;        o01 = dd0 + hh1;
        v02 = vd0 && vh2; o02 = dd0 + hh2;
        v10 = vh0;        o10 = dd1 + hh0;
        v11 = true;       o11 = dd1 + hh1;
        v12 = vh2;        o12 = dd1 + hh2;
        v20 = vd2 && vh0; o20 = dd2 + hh0;
        v21 = vd2;        o21 = dd2 + hh1;
        v22 = vd2 && vh2; o22 = dd2 + hh2;
    }
    const bool we0 = (w0 > 0);
    const bool we9 = (w0 < 88);
    const int  eo0 = we0 ? -1 : 0;
    const int  eo9 = we9 ?  8 : 7;

    float4 a0l={0,0,0,0}, a0h={0,0,0,0}, a1l={0,0,0,0}, a1h={0,0,0,0};
    float4 a2l={0,0,0,0}, a2h={0,0,0,0}, a3l={0,0,0,0}, a3h={0,0,0,0};

    for (int ci = 0; ci < 4; ++ci) {
        for (int i = 0; i < 3; ++i) {
            for (int j = 0; j < 3; ++j) {
                const float* xp  = xb + (size_t)ci*4718592
                                      + (size_t)(c + i)*589824
                                      + (size_t)(t + j)*73728;
                const float* wlp = &wl[(ci*9 + i*3 + j) * 108];

                // 2-plane lookahead pipeline (max 6 rows = 60 floats live)
                Row r00 = load_row(v00 ? xp + o00 : zb, eo0, eo9, we0, we9);
                Row r01 = load_row(v01 ? xp + o01 : zb, eo0, eo9, we0, we9);
                Row r02 = load_row(v02 ? xp + o02 : zb, eo0, eo9, we0, we9);
                Row r10 = load_row(v10 ? xp + o10 : zb, eo0, eo9, we0, we9);
                Row r11 = load_row(v11 ? xp + o11 : zb, eo0, eo9, we0, we9);
                Row r12 = load_row(v12 ? xp + o12 : zb, eo0, eo9, we0, we9);
                ROWC(r00, wlp +  0);
                ROWC(r01, wlp + 12);
                ROWC(r02, wlp + 24);
                Row r20 = load_row(v20 ? xp + o20 : zb, eo0, eo9, we0, we9);
                Row r21 = load_row(v21 ? xp + o21 : zb, eo0, eo9, we0, we9);
                Row r22 = load_row(v22 ? xp + o22 : zb, eo0, eo9, we0, we9);
                ROWC(r10, wlp + 36);
                ROWC(r11, wlp + 48);
                ROWC(r12, wlp + 60);
                ROWC(r20, wlp + 72);
                ROWC(r21, wlp + 84);
                ROWC(r22, wlp + 96);
            }
        }
    }

    // mean bias over the 9 (i,j) taps
    float mb0=0,mb1=0,mb2=0,mb3=0;
    #pragma unroll
    for (int ij = 0; ij < 9; ++ij) {
        mb0 += bg[ij*4+0]; mb1 += bg[ij*4+1];
        mb2 += bg[ij*4+2]; mb3 += bg[ij*4+3];
    }
    const float inv9 = 1.0f / 9.0f;
    mb0 *= inv9; mb1 *= inv9; mb2 *= inv9; mb3 *= inv9;

    size_t obase = (size_t)b*10616832 + (size_t)c*442368 + (size_t)t*73728
                 + (size_t)d*9216 + (size_t)h*96 + (size_t)w0;
    float* op;
    float4 r0, r1;
    op = outg + obase;
    r0 = make_float4(a0l.x*inv9+mb0, a0l.y*inv9+mb0, a0l.z*inv9+mb0, a0l.w*inv9+mb0);
    r1 = make_float4(a0h.x*inv9+mb0, a0h.y*inv9+mb0, a0h.z*inv9+mb0, a0h.w*inv9+mb0);
    *(float4*)op = r0; *(float4*)(op+4) = r1;
    op = outg + obase + 2654208;
    r0 = make_float4(a1l.x*inv9+mb1, a1l.y*inv9+mb1, a1l.z*inv9+mb1, a1l.w*inv9+mb1);
    r1 = make_float4(a1h.x*inv9+mb1, a1h.y*inv9+mb1, a1h.z*inv9+mb1, a1h.w*inv9+mb1);
    *(float4*)op = r0; *(float4*)(op+4) = r1;
    op = outg + obase + 2*2654208;
    r0 = make_float4(a2l.x*inv9+mb2, a2l.y*inv9+mb2, a2l.z*inv9+mb2, a2l.w*inv9+mb2);
    r1 = make_float4(a2h.x*inv9+mb2, a2h.y*inv9+mb2, a2h.z*inv9+mb2, a2h.w*inv9+mb2);
    *(float4*)op = r0; *(float4*)(op+4) = r1;
    op = outg + obase + 3*2654208;
    r0 = make_float4(a3l.x*inv9+mb3, a3l.y*inv9+mb3, a3l.z*inv9+mb3, a3l.w*inv9+mb3);
    r1 = make_float4(a3h.x*inv9+mb3, a3h.y*inv9+mb3, a3h.z*inv9+mb3, a3h.w*inv9+mb3);
    *(float4*)op = r0; *(float4*)(op+4) = r1;
}

extern "C" void kernel_launch(void* const* d_in, const int* in_sizes, int n_in,
                              void* d_out, int out_size, void* d_ws, size_t ws_size,
                              hipStream_t stream) {
    const float* x = (const float*)d_in[0];
    const float* W = (const float*)d_in[1];
    const float* b = (const float*)d_in[2];
    float* out = (float*)d_out;
    conv5d_kernel<<<2592, BLOCK, 0, stream>>>(x, W, b, out);
}

// Round 4
// 853.531 us; speedup vs baseline: 1.4478x; 1.4478x over previous
//
#include <hip/hip_runtime.h>

// x:   (2,4,8,8,8,96,96) fp32   strides: b 18874368, ci 4718592, cd 589824, t 73728, d 9216, h 96, w 1
// W:   (9,4,4,3,3,3)     fp32   strides: ij 432, o 108, ci 27, kd 9, kh 3, kw 1
// b:   (9,4)             fp32
// out: (2,4,6,6,8,96,96) fp32   strides: b 10616832, o 2654208, c 442368, t 73728, d 9216, h 96, w 1
//
// Block = (b,c,t,d, h-tile of 16). 256 threads: wt=tid&15 (6-wide w tile),
// hr_out=tid>>4 (h row). Per (ci,i,j): cooperatively stage 3 d-planes x 18
// h-rows x 96 w into LDS (coalesced float4), then compute from LDS with
// immediate-offset ds_reads. Row stride 104 floats; row origin at w=-4 so
// w=0 lands at index 4 (16B aligned stores); w=-1 / w=96 halo at idx 3/100
// are pre-zeroed once (never overwritten: staging writes idx 4..99 only).

#define BLOCK 256

__global__ __launch_bounds__(256, 4) void conv5d_kernel(
    const float* __restrict__ xg,
    const float* __restrict__ Wg,
    const float* __restrict__ bg,
    float* __restrict__ outg)
{
    __shared__ float wl[3888];       // weights: [ci][ij][kd][kh][kw][o]
    __shared__ float xs[54 * 104];   // x tile: [pl(3)][hr(18)][wcol(104)]

    for (int k = threadIdx.x; k < 3888; k += BLOCK) {
        int o  = k & 3;  int r = k >> 2;
        int kw = r % 3;  r /= 3;
        int kh = r % 3;  r /= 3;
        int kd = r % 3;  r /= 3;
        int ij = r % 9;  int ci = r / 9;
        wl[k] = Wg[ij*432 + o*108 + ci*27 + kd*9 + kh*3 + kw];
    }
    // zero the w-halo columns once (w=-1 at idx 3, w=96 at idx 100)
    for (int r = threadIdx.x; r < 54; r += BLOCK) {
        xs[r*104 + 3]   = 0.f;
        xs[r*104 + 100] = 0.f;
    }
    __syncthreads();

    // Block decode with XCD-aware swizzle: 3456 blocks = 72 (b,c,t) slabs x
    // 48 (d,ht). Each XCD (bi&7) gets 9 contiguous slabs -> its co-resident
    // blocks share input planes in its 4 MB L2.
    int bi   = blockIdx.x;
    int xcd  = bi & 7;
    int g    = bi >> 3;              // 0..431
    int slab = xcd*9 + g/48;         // 0..71
    int r2   = g % 48;
    int d    = r2 / 6;               // 0..7
    int ht   = r2 % 6;               // 0..5
    int b    = slab / 36;
    int ct   = slab % 36;
    int c    = ct / 6;
    int t    = ct % 6;
    int h0   = ht * 16;

    int wt     = threadIdx.x & 15;   // w tile: w0 = 6*wt
    int hr_out = threadIdx.x >> 4;   // 0..15

    float acc[4][6] = {};

    #pragma unroll 1
    for (int ci = 0; ci < 4; ++ci) {
        #pragma unroll 1
        for (int i = 0; i < 3; ++i) {
            #pragma unroll 1
            for (int j = 0; j < 3; ++j) {
                const float* xp = xg + (size_t)b*18874368 + (size_t)ci*4718592
                                     + (size_t)(c + i)*589824
                                     + (size_t)(t + j)*73728;

                __syncthreads();   // previous iter's readers done before overwrite

                // ---- stage: 54 rows x 24 float4 (coalesced), zeros for
                // ---- out-of-range d/h rows
                for (int u = threadIdx.x; u < 1296; u += BLOCK) {
                    int row = u / 24;          // 0..53
                    int q   = u % 24;
                    int pl  = row / 18;        // 0..2 (d-1, d, d+1)
                    int hr  = row % 18;        // 0..17 (h0-1 .. h0+16)
                    int dd  = d + pl - 1;
                    int hh  = h0 + hr - 1;
                    bool val = ((unsigned)dd < 8u) && ((unsigned)hh < 96u);
                    const float4* src = (const float4*)(xp
                        + (val ? dd : 0)*9216 + (val ? hh : 0)*96 + q*4);
                    float4 v = *src;
                    if (!val) v = make_float4(0.f, 0.f, 0.f, 0.f);
                    *(float4*)&xs[row*104 + 4 + q*4] = v;
                }

                __syncthreads();

                // ---- compute: 9 rows x (3 kw x 6 w x 4 o) = 648 FMAs
                const float* wq = &wl[(ci*9 + i*3 + j) * 108];
                #pragma unroll
                for (int pl = 0; pl < 3; ++pl) {
                    #pragma unroll
                    for (int kh = 0; kh < 3; ++kh) {
                        // taps w0-1..w0+6 -> xs idx (w0+3)..(w0+10)
                        const float* xr = &xs[(pl*18 + hr_out + kh)*104 + 3 + 6*wt];
                        float x0 = xr[0], x1 = xr[1], x2 = xr[2], x3 = xr[3];
                        float x4 = xr[4], x5 = xr[5], x6 = xr[6], x7 = xr[7];
                        float xv[8] = {x0, x1, x2, x3, x4, x5, x6, x7};
                        const float* wr = wq + (pl*9 + kh*3)*4;
                        float4 wk0 = ((const float4*)wr)[0];
                        float4 wk1 = ((const float4*)wr)[1];
                        float4 wk2 = ((const float4*)wr)[2];
                        #pragma unroll
                        for (int v = 0; v < 6; ++v) {
                            float a = xv[v], bb = xv[v+1], cc = xv[v+2];
                            acc[0][v] = fmaf(a,  wk0.x, acc[0][v]);
                            acc[1][v] = fmaf(a,  wk0.y, acc[1][v]);
                            acc[2][v] = fmaf(a,  wk0.z, acc[2][v]);
                            acc[3][v] = fmaf(a,  wk0.w, acc[3][v]);
                            acc[0][v] = fmaf(bb, wk1.x, acc[0][v]);
                            acc[1][v] = fmaf(bb, wk1.y, acc[1][v]);
                            acc[2][v] = fmaf(bb, wk1.z, acc[2][v]);
                            acc[3][v] = fmaf(bb, wk1.w, acc[3][v]);
                            acc[0][v] = fmaf(cc, wk2.x, acc[0][v]);
                            acc[1][v] = fmaf(cc, wk2.y, acc[1][v]);
                            acc[2][v] = fmaf(cc, wk2.z, acc[2][v]);
                            acc[3][v] = fmaf(cc, wk2.w, acc[3][v]);
                        }
                    }
                }
            }
        }
    }

    // mean bias over the 9 (i,j) taps
    float mb[4];
    #pragma unroll
    for (int o = 0; o < 4; ++o) {
        float s = 0.f;
        #pragma unroll
        for (int ij = 0; ij < 9; ++ij) s += bg[ij*4 + o];
        mb[o] = s * (1.0f / 9.0f);
    }

    const float inv9 = 1.0f / 9.0f;
    size_t obase = (size_t)b*10616832 + (size_t)c*442368 + (size_t)t*73728
                 + (size_t)d*9216 + (size_t)(h0 + hr_out)*96 + 6*wt;
    #pragma unroll
    for (int o = 0; o < 4; ++o) {
        float* op = outg + obase + (size_t)o*2654208;
        #pragma unroll
        for (int v = 0; v < 3; ++v) {
            float2 st;
            st.x = acc[o][2*v]   * inv9 + mb[o];
            st.y = acc[o][2*v+1] * inv9 + mb[o];
            *(float2*)(op + 2*v) = st;
        }
    }
}

extern "C" void kernel_launch(void* const* d_in, const int* in_sizes, int n_in,
                              void* d_out, int out_size, void* d_ws, size_t ws_size,
                              hipStream_t stream) {
    const float* x = (const float*)d_in[0];
    const float* W = (const float*)d_in[1];
    const float* b = (const float*)d_in[2];
    float* out = (float*)d_out;
    conv5d_kernel<<<3456, BLOCK, 0, stream>>>(x, W, b, out);
}